// Round 8
// baseline (124.767 us; speedup 1.0000x reference)
//
#include <hip/hip_runtime.h>
#include <hip/hip_bf16.h>
#include <math.h>

#define Bn 4
#define Cn 64
#define Pn 4096   // 64*64
#define QT 64     // q-tile per block
#define PBK 128   // p-block per flash iteration
#define PHALF 2048            // R20: p-range per block (2-way p-split)
#define NITER (PHALF / PBK)   // 16
#define LOG2E 1.4426950408889634f

typedef __attribute__((ext_vector_type(8))) short short8;   // 8 bf16 (MFMA K=32 A/B frag)
typedef __attribute__((ext_vector_type(4))) short short4v;  // 4 bf16 (MFMA K=16 A/B frag)
typedef __attribute__((ext_vector_type(4))) float float4v;  // MFMA C/D frag
typedef unsigned short bfu;

__device__ __forceinline__ bfu f2bf(float x) {
    unsigned u = __float_as_uint(x);
    u = (u + 0x7fffu + ((u >> 16) & 1u)) >> 16;   // RNE; inputs finite
    return (bfu)u;
}

// ---------------------------------------------------------------------------
// Prep (unchanged): 768 blocks, 16KB LDS.
//   blocks [0,512):   knorm -> bf16 Kpc [B][P][C]  and tiled Kcp2 [B][P/16][C][16p]
//   blocks [512,768): 3x3 zero-padded box-sum * log2(e) -> S [B][C][P]
// ---------------------------------------------------------------------------
__global__ __launch_bounds__(256) void prep_kernel(const float* __restrict__ fg,
                                                   bfu* __restrict__ Kpc,
                                                   bfu* __restrict__ Kcp2,
                                                   float* __restrict__ S) {
    __shared__ float shbuf[64 * 64];
    int t = threadIdx.x;
    if (blockIdx.x < 512) {
        float* tile  = shbuf;            // [64c][32p] stride 33
        float* rnorm = shbuf + 64 * 33;
        int b  = blockIdx.x >> 7;
        int p0 = (blockIdx.x & 127) << 5;
        const float* src = fg + (size_t)b * Cn * Pn + p0;
        #pragma unroll
        for (int i = 0; i < 8; ++i) {
            int idx = i * 256 + t;
            int c = idx >> 5, p = idx & 31;
            tile[c * 33 + p] = src[(size_t)c * Pn + p];
        }
        __syncthreads();
        if (t < 32) {
            float ss = 0.f;
            #pragma unroll
            for (int c = 0; c < 64; ++c) { float v = tile[c * 33 + t]; ss += v * v; }
            rnorm[t] = 1.0f / (sqrtf(ss) + 1e-8f);
        }
        __syncthreads();
        bfu* dpc = Kpc + ((size_t)b * Pn + p0) * Cn;
        #pragma unroll
        for (int i = 0; i < 8; ++i) {
            int idx = i * 256 + t;
            int p = idx >> 6, c = idx & 63;
            dpc[(size_t)p * Cn + c] = f2bf(tile[c * 33 + p] * rnorm[p]);
        }
        // tiled transpose layout: Kcp2[b][pt][c][pl], pt = p>>4, pl = p&15
        bfu* d2 = Kcp2 + ((size_t)b * 256 + (p0 >> 4)) * 1024;
        #pragma unroll
        for (int i = 0; i < 8; ++i) {
            int idx = i * 256 + t;
            int c = idx >> 5, p = idx & 31;
            d2[(size_t)(p >> 4) * 1024 + c * 16 + (p & 15)] =
                f2bf(tile[c * 33 + p] * rnorm[p]);
        }
    } else {
        float (*pl)[64] = (float(*)[64])shbuf;
        int bc = blockIdx.x - 512;
        const float* src = fg + (size_t)bc * Pn;
        float*       dst = S  + (size_t)bc * Pn;
        #pragma unroll
        for (int i = 0; i < 16; ++i) {
            int idx = i * 256 + t;
            pl[idx >> 6][idx & 63] = src[idx];
        }
        __syncthreads();
        #pragma unroll
        for (int i = 0; i < 16; ++i) {
            int idx = i * 256 + t;
            int h = idx >> 6, w = idx & 63;
            float s = 0.f;
            #pragma unroll
            for (int dh = -1; dh <= 1; ++dh) {
                int hh = h + dh;
                if (hh < 0 || hh >= 64) continue;
                #pragma unroll
                for (int dw = -1; dw <= 1; ++dw) {
                    int ww = w + dw;
                    if (ww < 0 || ww >= 64) continue;
                    s += pl[hh][ww];
                }
            }
            dst[idx] = s * LOG2E;
        }
    }
}

// ---------------------------------------------------------------------------
// Flash (R20) = R0 champion K-loop, p-SPLIT 2-way: grid 512, block (b,qt,half)
// covers 64 q x 2048 p. 2 blocks/CU -> 4 waves/SIMD at UNCHANGED total L2
// traffic (the occupancy-vs-L2-bandwidth disambiguation experiment; R15 had
// 4 waves/SIMD but 2x traffic). Writes fp32 O-partials and l-partials; a
// combine kernel finishes (O0+O1)/(l0+l1).
// Wave w owns p-rows [16w,16w+16) of each 128-p block end-to-end:
//   score: A = global Kpc rows (dwordx4), B = hoisted S frags (K=32 MFMA x8)
//   exp'd scores -> register K=16 A-frags (C-layout == A-layout)
//   accum: B = global Kcp2 frags (dwordx2), K=16 MFMA x16; loads prefetched
//   one iteration ahead. No LDS, no barriers inside the loop.
// ---------------------------------------------------------------------------
__global__ __launch_bounds__(512, 4) void flash_kernel(const bfu* __restrict__ Kpc,
                                                       const bfu* __restrict__ Kcp2,
                                                       const float* __restrict__ S,
                                                       float* __restrict__ Opart,
                                                       float* __restrict__ lpart) {
    // Sl lives in [0,8192) bfu; epilogue Ol fp32 [4][64][66] overlays all 67.5 KB
    __shared__ __align__(16) bfu smem[33792];
    __shared__ float wredl[8][QT];
    bfu* Sl = smem;

    int i    = blockIdx.x;
    int half = i >> 8;                           // p-split half: [0,2048) or [2048,4096)
    int j    = i & 255;
    int b  = (j & 7) >> 1;                       // XCD-pair locality (i and i+256 same XCD)
    int qt = ((j >> 3) << 1) | (j & 1);
    int q0 = qt * QT;
    int t  = threadIdx.x;
    int w = t >> 6, l = t & 63, lq = l & 15, quad = l >> 4;

    const float* Sg  = S    + (size_t)b * Cn * Pn;
    const bfu*   gpc = Kpc  + (size_t)b * Pn * Cn + (size_t)half * PHALF * Cn;
    const bfu*   gt  = Kcp2 + (size_t)b * 256 * 1024 + (size_t)half * 128 * 1024;  // [pt][c][pl]

    // Sl[q][c] = bf16(Sg[c][q0+q]) (S pre-scaled by log2e), XOR-swizzled rows
    {
        int c = t >> 3, qq = (t & 7) * 8;
        const float* sp = &Sg[(size_t)c * Pn + q0 + qq];
        float4 v0 = *(const float4*)sp;
        float4 v1 = *(const float4*)(sp + 4);
        float vv[8] = {v0.x, v0.y, v0.z, v0.w, v1.x, v1.y, v1.z, v1.w};
        int ch = c >> 3, cl = c & 7;
        #pragma unroll
        for (int k = 0; k < 8; ++k) {
            int row = qq + k;
            Sl[row * 64 + ((ch ^ (row & 7)) << 3) + cl] = f2bf(vv[k]);
        }
    }
    __syncthreads();   // Sl visible

    // hoist S B-frags: B[k=c][n=q], n=lq(+16nt), k=quad*8+j (+32ks)
    short8 bs[4][2];
    #pragma unroll
    for (int nt = 0; nt < 4; ++nt)
        #pragma unroll
        for (int ks = 0; ks < 2; ++ks) {
            int row = nt * 16 + lq;
            bs[nt][ks] = *(const short8*)&Sl[row * 64 + (((ks * 4 + quad) ^ (lq & 7)) << 3)];
        }

    float4v o[4][4];   // [nt][cb]: q = 16nt+4quad+r, c = 16cb+lq (wave-private p-partial)
    #pragma unroll
    for (int nt = 0; nt < 4; ++nt)
        #pragma unroll
        for (int cb = 0; cb < 4; ++cb) o[nt][cb] = (float4v){0.f, 0.f, 0.f, 0.f};
    float lacc[4] = {0.f, 0.f, 0.f, 0.f};

    // per-wave global addresses (advance by constants each iteration)
    const bfu* ap = gpc + ((size_t)16 * w + lq) * Cn + quad * 8;           // score A rows
    const bfu* tp = gt + (size_t)w * 1024 + lq * 16 + quad * 4;            // accum B frags

    // prologue: load pb=0 operands
    float4 a0 = *(const float4*)ap;
    float4 a1 = *(const float4*)(ap + 32);
    short4v kb[4];
    #pragma unroll
    for (int cb = 0; cb < 4; ++cb) kb[cb] = *(const short4v*)(tp + cb * 256);

    for (int pb = 0; pb < NITER; ++pb) {
        // ---- prefetch pb+1 operands (independent; compiler issues early) ----
        float4 na0, na1;
        short4v nkb[4];
        if (pb + 1 < NITER) {
            const bfu* apn = ap + (size_t)(pb + 1) * PBK * Cn;
            na0 = *(const float4*)apn;
            na1 = *(const float4*)(apn + 32);
            const bfu* tpn = tp + (size_t)(pb + 1) * 8 * 1024;
            #pragma unroll
            for (int cb = 0; cb < 4; ++cb) nkb[cb] = *(const short4v*)(tpn + cb * 256);
        }

        // ---- score GEMM (K=32): D[m=p][n=q], 4 q-subtiles ----
        short8 af0 = *(short8*)&a0, af1 = *(short8*)&a1;
        float4v sc[4];
        #pragma unroll
        for (int nt = 0; nt < 4; ++nt) {
            float4v acc = (float4v){0.f, 0.f, 0.f, 0.f};
            acc = __builtin_amdgcn_mfma_f32_16x16x32_bf16(af0, bs[nt][0], acc, 0, 0, 0);
            acc = __builtin_amdgcn_mfma_f32_16x16x32_bf16(af1, bs[nt][1], acc, 0, 0, 0);
            sc[nt] = acc;
        }

        // ---- exp2 + denominator; pack E directly as K=16 A-frags ----
        short4v epk[4];
        #pragma unroll
        for (int nt = 0; nt < 4; ++nt) {
            float e0 = __builtin_amdgcn_exp2f(sc[nt][0]);
            float e1 = __builtin_amdgcn_exp2f(sc[nt][1]);
            float e2 = __builtin_amdgcn_exp2f(sc[nt][2]);
            float e3 = __builtin_amdgcn_exp2f(sc[nt][3]);
            lacc[nt] += (e0 + e1) + (e2 + e3);
            short4v ep = {(short)f2bf(e0), (short)f2bf(e1), (short)f2bf(e2), (short)f2bf(e3)};
            epk[nt] = ep;
        }

        // ---- accum GEMM (K=16): o'[q][c] += E · Kcp2 frags ----
        #pragma unroll
        for (int cb = 0; cb < 4; ++cb) {
            #pragma unroll
            for (int nt = 0; nt < 4; ++nt)
                o[nt][cb] = __builtin_amdgcn_mfma_f32_16x16x16bf16_1k(epk[nt], kb[cb], o[nt][cb], 0, 0, 0);
        }

        // rotate prefetched operands
        a0 = na0; a1 = na1;
        #pragma unroll
        for (int cb = 0; cb < 4; ++cb) kb[cb] = nkb[cb];
    }

    // ---- denominator: quad-reduce then stash per wave ----
    #pragma unroll
    for (int nt = 0; nt < 4; ++nt) {
        lacc[nt] += __shfl_xor(lacc[nt], 16);
        lacc[nt] += __shfl_xor(lacc[nt], 32);
    }
    if (quad == 0)
        #pragma unroll
        for (int nt = 0; nt < 4; ++nt) wredl[w][nt * 16 + lq] = lacc[nt];

    // ---- cross-wave combine via LDS overlay (2 rounds) ----
    float* Ol = (float*)smem;   // [4][64 c][66] fp32 = 67584 B
    __syncthreads();            // Sl reads done; wredl visible
    if (w < 4) {
        #pragma unroll
        for (int nt = 0; nt < 4; ++nt)
            #pragma unroll
            for (int cb = 0; cb < 4; ++cb)
                #pragma unroll
                for (int r = 0; r < 4; ++r)
                    Ol[(w * 64 + 16 * cb + lq) * 66 + nt * 16 + quad * 4 + r] = o[nt][cb][r];
    }
    __syncthreads();
    if (w >= 4) {
        #pragma unroll
        for (int nt = 0; nt < 4; ++nt)
            #pragma unroll
            for (int cb = 0; cb < 4; ++cb)
                #pragma unroll
                for (int r = 0; r < 4; ++r)
                    Ol[((w - 4) * 64 + 16 * cb + lq) * 66 + nt * 16 + quad * 4 + r] += o[nt][cb][r];
    }
    __syncthreads();

    // ---- final: write fp32 partials (no divide) ----
    float* Og = Opart + (size_t)(half * Bn + b) * Cn * Pn;
    #pragma unroll
    for (int k = 0; k < 8; ++k) {
        int idx = k * 512 + t;
        int c = idx >> 6, q = idx & 63;
        float v = ((Ol[c * 66 + q] + Ol[(64 + c) * 66 + q]) +
                   (Ol[(128 + c) * 66 + q] + Ol[(192 + c) * 66 + q]));
        Og[(size_t)c * Pn + q0 + q] = v;
    }
    if (t < QT) {
        float ls = ((wredl[0][t] + wredl[1][t]) + (wredl[2][t] + wredl[3][t])) +
                   ((wredl[4][t] + wredl[5][t]) + (wredl[6][t] + wredl[7][t]));
        lpart[(size_t)(half * Bn + b) * Pn + q0 + t] = ls;
    }
}

// ---------------------------------------------------------------------------
// Combine: out[b][c][q] = (O0+O1)/(l0+l1). 1024 blocks x 256 thr, float4.
// ---------------------------------------------------------------------------
__global__ __launch_bounds__(256) void combine_kernel(const float* __restrict__ Opart,
                                                      const float* __restrict__ lpart,
                                                      float* __restrict__ out) {
    const int BCP = Bn * Cn * Pn;   // 1M
    int idx = (blockIdx.x * 256 + threadIdx.x) * 4;
    int b = idx >> 18;              // Cn*Pn = 262144
    int q = idx & (Pn - 1);
    float4 o0 = *(const float4*)(Opart + idx);
    float4 o1 = *(const float4*)(Opart + BCP + idx);
    float4 l0 = *(const float4*)(lpart + (size_t)b * Pn + q);
    float4 l1 = *(const float4*)(lpart + (size_t)(Bn + b) * Pn + q);
    float4 r;
    r.x = (o0.x + o1.x) / (l0.x + l1.x);
    r.y = (o0.y + o1.y) / (l0.y + l1.y);
    r.z = (o0.z + o1.z) / (l0.z + l1.z);
    r.w = (o0.w + o1.w) / (l0.w + l1.w);
    *(float4*)(out + idx) = r;
}

// ---------------------------------------------------------------------------
extern "C" void kernel_launch(void* const* d_in, const int* in_sizes, int n_in,
                              void* d_out, int out_size, void* d_ws, size_t ws_size,
                              hipStream_t stream) {
    const float* fg = (const float*)d_in[0];
    float* out = (float*)d_out;
    bfu*   Kpc   = (bfu*)d_ws;                              // 2 MB  bf16 [B][P][C]
    bfu*   Kcp2  = Kpc + (size_t)Bn * Pn * Cn;              // 2 MB  bf16 [B][P/16][C][16]
    float* S     = (float*)(Kcp2 + (size_t)Bn * Pn * Cn);   // 4 MB  fp32 [B][C][P] (pre-scaled by log2e)
    float* Opart = S + (size_t)Bn * Cn * Pn;                // 8 MB  fp32 [2][B][C][P]
    float* lpart = Opart + 2 * (size_t)Bn * Cn * Pn;        // 128KB fp32 [2][B][P]

    prep_kernel   <<<768, 256, 0, stream>>>(fg, Kpc, Kcp2, S);
    flash_kernel  <<<512, 512, 0, stream>>>(Kpc, Kcp2, S, Opart, lpart);
    combine_kernel<<<1024, 256, 0, stream>>>(Opart, lpart, out);
}